// Round 6
// baseline (332.415 us; speedup 1.0000x reference)
//
#include <hip/hip_runtime.h>
#include <stdint.h>

// SelfAttentionLayer: x [32,32,32,512] fp32 -> out fp32 same shape
#define B_ 32
#define N_ 1024   // tokens per batch (H*W)
#define C_ 512
#define D_ 64     // DQK

typedef __attribute__((ext_vector_type(8))) __bf16 bf8;   // MFMA A/B frag (4 VGPRs)
typedef __attribute__((ext_vector_type(4))) float f32x4;  // MFMA C/D frag

typedef const __attribute__((address_space(1))) void* gp_t;
typedef __attribute__((address_space(3))) void* lp_t;

__device__ inline void g2l16(const void* g, void* l) {
    // async global->LDS, 16B/lane; LDS dest = uniform base + lane*16
    __builtin_amdgcn_global_load_lds((gp_t)g, (lp_t)l, 16, 0, 0);
}

__device__ inline float b2f(unsigned short u) {
    return __uint_as_float(((unsigned)u) << 16);
}
__device__ inline unsigned short f2b(float f) {   // f32 -> bf16 bits, RNE
    unsigned u = __float_as_uint(f);
    u += 0x7FFF + ((u >> 16) & 1);
    return (unsigned short)(u >> 16);
}

#define MFMA16(a, b, c) __builtin_amdgcn_mfma_f32_16x16x32_bf16((a), (b), (c), 0, 0, 0)

// fragment loads from a staged (frag-order) 128x64 tile pair
__device__ __forceinline__ void ld_frags(const unsigned short* As, const unsigned short* Bs,
                                         int wm, int wn, int lane,
                                         bf8 (&a)[2][4], bf8 (&bb)[2][4]) {
    #pragma unroll
    for (int kq = 0; kq < 2; ++kq) {
        #pragma unroll
        for (int ti = 0; ti < 4; ++ti)
            a[kq][ti] = *(const bf8*)&As[((wm * 4 + ti) * 2 + kq) * 512 + lane * 8];
        #pragma unroll
        for (int tj = 0; tj < 4; ++tj)
            bb[kq][tj] = *(const bf8*)&Bs[((wn * 4 + tj) * 2 + kq) * 512 + lane * 8];
    }
}

__device__ __forceinline__ void do_mfma(const bf8 (&a)[2][4], const bf8 (&bb)[2][4],
                                        f32x4 (&acc)[4][4]) {
    #pragma unroll
    for (int kq = 0; kq < 2; ++kq)
        #pragma unroll
        for (int ti = 0; ti < 4; ++ti)
            #pragma unroll
            for (int tj = 0; tj < 4; ++tj)
                acc[ti][tj] = MFMA16(a[kq][ti], bb[kq][tj], acc[ti][tj]);
}

// ---------------------------------------------------------------------------
// Kernel 0: x fp32 -> bf16 (so qkv can stage via global_load_lds)
// ---------------------------------------------------------------------------
__global__ __launch_bounds__(256) void xcvt(const float* __restrict__ x,
                                            unsigned short* __restrict__ xb) {
    int i = blockIdx.x * 256 + threadIdx.x;      // quad index, exact grid
    float4 f = ((const float4*)x)[i];
    ushort4 o;
    o.x = f2b(f.x); o.y = f2b(f.y); o.z = f2b(f.z); o.w = f2b(f.w);
    ((ushort4*)xb)[i] = o;
}

// ---------------------------------------------------------------------------
// Kernel 0b: weight transpose + cvt into concatenated WT[640][512] bf16.
// ---------------------------------------------------------------------------
__global__ __launch_bounds__(256) void wtrans_all(
    const float* __restrict__ wq, const float* __restrict__ wk,
    const float* __restrict__ wv, unsigned short* __restrict__ wt)
{
    int t = blockIdx.x * 256 + threadIdx.x;      // output-linear, exact grid (640*512)
    int co = t >> 9;          // /512
    int ci = t & 511;
    const float* src;
    int col, cout;
    if (co < 64)       { src = wq; col = co;       cout = 64;  }
    else if (co < 128) { src = wk; col = co - 64;  cout = 64;  }
    else               { src = wv; col = co - 128; cout = 512; }
    wt[t] = f2b(src[(size_t)ci * cout + col]);
}

// ---------------------------------------------------------------------------
// Kernel 1: QKV projection GEMM. [32768,512]bf16 @ WT[640,512]^T.
// (round-2 structure — 2-deep counted-vmcnt pipeline; unchanged)
// ---------------------------------------------------------------------------
__global__ __launch_bounds__(256) void qkv(
    const unsigned short* __restrict__ xb,
    const unsigned short* __restrict__ WT,
    const float* __restrict__ bq, const float* __restrict__ bk,
    const float* __restrict__ bv,
    unsigned short* __restrict__ q, unsigned short* __restrict__ k,
    unsigned short* __restrict__ vT)
{
    const int rb = blockIdx.x;
    const int cb = blockIdx.y;
    const int tid = threadIdx.x;
    const int lane = tid & 63;
    const int wave = tid >> 6;
    const int wm = wave >> 1, wn = wave & 1;
    const int lr = lane & 15;     // frag row/col within 16
    const int lk = lane >> 4;     // k-octet 0..3

    __shared__ unsigned short SM[32768];      // 64 KB: As[2][8192] | Bs[2][8192]
    unsigned short* TB = SM;                  // aliased transpose buf 128x132 (16896)

    const int row0 = rb * 128;
    const int col0 = cb * 128;                // within [640]

    f32x4 zero4 = {0.f, 0.f, 0.f, 0.f};
    f32x4 acc[4][4];
    #pragma unroll
    for (int i = 0; i < 4; ++i)
        #pragma unroll
        for (int j = 0; j < 4; ++j) acc[i][j] = zero4;

    auto stage = [&](int buf, int kk) {       // 8 loads/wave
        unsigned short* As = SM + buf * 8192;
        unsigned short* Bs = SM + 16384 + buf * 8192;
        #pragma unroll
        for (int i = 0; i < 4; ++i) {          // 16 frags each for A and B
            int f = wave * 4 + i;
            int t = f >> 1, kq = f & 1;
            g2l16(xb + (size_t)(row0 + t * 16 + lr) * C_ + kk + kq * 32 + lk * 8,
                  &As[f * 512]);
            g2l16(WT + (size_t)(col0 + t * 16 + lr) * C_ + kk + kq * 32 + lk * 8,
                  &Bs[f * 512]);
        }
    };

    stage(0, 0);
    stage(1, 64);
    int cur = 0;
    for (int t = 0; t < 6; ++t) {             // steady state: tiles 0..5
        asm volatile("s_waitcnt vmcnt(8)" ::: "memory");   // tile t landed
        __builtin_amdgcn_s_barrier();
        bf8 a[2][4], bb[2][4];
        ld_frags(SM + cur * 8192, SM + 16384 + cur * 8192, wm, wn, lane, a, bb);
        asm volatile("s_waitcnt lgkmcnt(0)" ::: "memory"); // my reads done
        __builtin_amdgcn_s_barrier();                       // everyone's reads done
        stage(cur, (t + 2) * 64);             // reuse buffer for tile t+2
        do_mfma(a, bb, acc);
        cur ^= 1;
    }
    {   // tile 6: wait oldest 8, tile 7 still in flight
        asm volatile("s_waitcnt vmcnt(8)" ::: "memory");
        __builtin_amdgcn_s_barrier();
        bf8 a[2][4], bb[2][4];
        ld_frags(SM + cur * 8192, SM + 16384 + cur * 8192, wm, wn, lane, a, bb);
        do_mfma(a, bb, acc);
        cur ^= 1;
    }
    {   // tile 7: final drain
        asm volatile("s_waitcnt vmcnt(0)" ::: "memory");
        __builtin_amdgcn_s_barrier();
        bf8 a[2][4], bb[2][4];
        ld_frags(SM + cur * 8192, SM + 16384 + cur * 8192, wm, wn, lane, a, bb);
        do_mfma(a, bb, acc);
    }

    if (cb == 0) {
        // wn==0 waves own cols 0..63 (-> q), wn==1 own cols 64..127 (-> k)
        unsigned short* outp = (wn == 0) ? q : k;
        const float* bias = (wn == 0) ? bq : bk;
        #pragma unroll
        for (int ti = 0; ti < 4; ++ti)
            #pragma unroll
            for (int tj = 0; tj < 4; ++tj) {
                int col = tj * 16 + lr;           // 0..63 within q or k
                float bi = bias[col];
                #pragma unroll
                for (int r = 0; r < 4; ++r) {
                    int row = row0 + wm * 64 + ti * 16 + lk * 4 + r;
                    outp[(size_t)row * D_ + col] = f2b(acc[ti][tj][r] + bi);
                }
            }
    } else {
        const int colv = (cb - 1) * 128;          // v col base (0..511)
        __syncthreads();                          // all frag reads done; TB aliases SM
        #pragma unroll
        for (int ti = 0; ti < 4; ++ti)
            #pragma unroll
            for (int tj = 0; tj < 4; ++tj) {
                int c = wn * 64 + tj * 16 + lr;   // 0..127 within block
                float bi = bv[colv + c];
                int tok = wm * 64 + ti * 16 + lk * 4;
                ushort4 o;
                o.x = f2b(acc[ti][tj][0] + bi);
                o.y = f2b(acc[ti][tj][1] + bi);
                o.z = f2b(acc[ti][tj][2] + bi);
                o.w = f2b(acc[ti][tj][3] + bi);
                *(ushort4*)&TB[c * 132 + tok] = o;
            }
        __syncthreads();
        const int b  = row0 >> 10;
        const int n0 = row0 & 1023;
        #pragma unroll
        for (int i = 0; i < 16; ++i) {
            int idx = tid + 256 * i;              // 0..4095
            int c = idx >> 5, ch = idx & 31;
            ushort4 t4 = *(const ushort4*)&TB[c * 132 + ch * 4];
            *(ushort4*)&vT[((size_t)(b * C_ + colv + c)) * N_ + n0 + ch * 4] = t4;
        }
    }
}

// ---------------------------------------------------------------------------
// Kernel 2: scores + softmax -> P bf16 [b][n][m].  (unchanged)
// ---------------------------------------------------------------------------
#define SLD 1032   // S leading dim (shorts), pad 8 to break 2048B bank period
__global__ __launch_bounds__(256) void scores(
    const unsigned short* __restrict__ q,
    const unsigned short* __restrict__ k,
    unsigned short* __restrict__ P)
{
    const int qt = blockIdx.x, b = blockIdx.y;
    const int tid = threadIdx.x, lane = tid & 63, wave = tid >> 6;
    const int lr = lane & 15, lk = lane >> 4;
    __shared__ unsigned short S[16 * SLD];      // bf16 scores, 33 KB

    const int n0 = qt * 16;
    const unsigned short* qrow = q + (size_t)(b * N_ + n0 + lr) * D_ + lk * 8;
    bf8 qa0 = *(const bf8*)(qrow);
    bf8 qa1 = *(const bf8*)(qrow + 32);

    const int m0w = wave * 256;
    #pragma unroll 4
    for (int mt = 0; mt < 16; ++mt) {
        int m = m0w + mt * 16;
        const unsigned short* krow = k + (size_t)(b * N_ + m + lr) * D_ + lk * 8;
        bf8 kb0 = *(const bf8*)(krow);
        bf8 kb1 = *(const bf8*)(krow + 32);
        f32x4 s = {0.f, 0.f, 0.f, 0.f};
        s = MFMA16(qa0, kb0, s);
        s = MFMA16(qa1, kb1, s);
        #pragma unroll
        for (int r = 0; r < 4; ++r)
            S[(lk * 4 + r) * SLD + m + lr] = f2b(s[r] * 0.125f);  // 1/sqrt(64)
    }
    __syncthreads();

    #pragma unroll
    for (int rr4 = 0; rr4 < 4; ++rr4) {
        int rr = wave * 4 + rr4;
        float vals[16];
        float mx = -1e30f;
        #pragma unroll
        for (int j = 0; j < 16; ++j) {
            vals[j] = b2f(S[rr * SLD + j * 64 + lane]);
            mx = fmaxf(mx, vals[j]);
        }
        #pragma unroll
        for (int off = 32; off; off >>= 1) mx = fmaxf(mx, __shfl_xor(mx, off));
        float sum = 0.f;
        #pragma unroll
        for (int j = 0; j < 16; ++j) { vals[j] = __expf(vals[j] - mx); sum += vals[j]; }
        #pragma unroll
        for (int off = 32; off; off >>= 1) sum += __shfl_xor(sum, off);
        float inv = 1.f / sum;
        unsigned short* pp = P + (size_t)(b * N_ + n0 + rr) * N_;
        #pragma unroll
        for (int j = 0; j < 16; ++j) pp[j * 64 + lane] = f2b(vals[j] * inv);
    }
}

// ---------------------------------------------------------------------------
// Kernel 3: O = P @ V + x (residual), fp32 out.  No-LDS direct-register
// GEMM.  Both P[m][k] and vT[c][k] are frag-contiguous (K contiguous in
// memory), so each lane's 16B fragment is one global_load_dwordx4 from the
// XCD-local L2 (round-4 batch placement kept).  No barriers, no LDS: the
// compiler pipelines iteration t+1's 16 loads under iteration t's 32 MFMAs.
// Each wave owns a 64x64 output tile.  grid = 1024 flat, XCD-bound decode.
// Addressing: single base + 32-bit byte offsets (folds to offset: imms).
// ---------------------------------------------------------------------------
__global__ __launch_bounds__(256) void pv(
    const unsigned short* __restrict__ P,
    const unsigned short* __restrict__ vT,
    const float* __restrict__ x,
    float* __restrict__ out)
{
    // XCD-bound swizzle: xcd = f&7 (dispatch round-robin), 4 batches/XCD.
    const int f_   = blockIdx.x;
    const int xcd  = f_ & 7;
    const int s_   = f_ >> 3;            // 0..127 slot within XCD
    const int b    = xcd * 4 + (s_ >> 5);    // batch (same-b => same xcd)
    const int w_   = s_ & 31;            // 0..31 tile within batch
    const int m0   = (w_ & 7) * 128;
    const int c0   = (w_ >> 3) * 128;

    const int tid = threadIdx.x, lane = tid & 63, wave = tid >> 6;
    const int wm = wave >> 1, wn = wave & 1;
    const int lr = lane & 15, lk = lane >> 4;

    f32x4 zero4 = {0.f, 0.f, 0.f, 0.f};
    f32x4 acc[4][4];
    #pragma unroll
    for (int i = 0; i < 4; ++i)
        #pragma unroll
        for (int j = 0; j < 4; ++j) acc[i][j] = zero4;

    // single per-lane base pointer per matrix; rows differ by constant strides
    const unsigned short* Pbase =
        P  + (size_t)(b * N_ + m0 + wm * 64 + lr) * N_ + lk * 8;
    const unsigned short* Vbase =
        vT + ((size_t)(b * C_ + c0 + wn * 64 + lr)) * N_ + lk * 8;

    for (int kk = 0; kk < N_; kk += 64) {
        bf8 a[2][4], bb[2][4];
        #pragma unroll
        for (int kq = 0; kq < 2; ++kq) {
            #pragma unroll
            for (int ti = 0; ti < 4; ++ti)
                a[kq][ti] = *(const bf8*)(Pbase + ti * 16 * N_ + kk + kq * 32);
            #pragma unroll
            for (int tj = 0; tj < 4; ++tj)
                bb[kq][tj] = *(const bf8*)(Vbase + tj * 16 * N_ + kk + kq * 32);
        }
        do_mfma(a, bb, acc);
    }

    #pragma unroll
    for (int ti = 0; ti < 4; ++ti)
        #pragma unroll
        for (int tj = 0; tj < 4; ++tj) {
            int col = c0 + wn * 64 + tj * 16 + lr;
            #pragma unroll
            for (int r = 0; r < 4; ++r) {
                int row = m0 + wm * 64 + ti * 16 + lk * 4 + r;
                size_t idx = (size_t)(b * N_ + row) * C_ + col;
                out[idx] = acc[ti][tj][r] + x[idx];
            }
        }
}

// ---------------------------------------------------------------------------
extern "C" void kernel_launch(void* const* d_in, const int* in_sizes, int n_in,
                              void* d_out, int out_size, void* d_ws, size_t ws_size,
                              hipStream_t stream) {
    (void)in_sizes; (void)n_in; (void)out_size; (void)ws_size;
    const float* xf = (const float*)d_in[0];
    const float* wq = (const float*)d_in[1];
    const float* bq = (const float*)d_in[2];
    const float* wk = (const float*)d_in[3];
    const float* bk = (const float*)d_in[4];
    const float* wv = (const float*)d_in[5];
    const float* bv = (const float*)d_in[6];
    float* out = (float*)d_out;

    // workspace layout (bytes), total needed ~109 MB:
    //   q [0,4MB) | k [4MB,8MB) | vT [8MB,40MB)
    //   WT (655KB) + xb (32MB) in [40MB, 76MB)  -- dead after qkv
    //   P (64MB) aliased over WT+xb region starting 41,943,040
    char* ws = (char*)d_ws;
    unsigned short* qb  = (unsigned short*)(ws);
    unsigned short* kb  = (unsigned short*)(ws + 4194304);
    unsigned short* vTb = (unsigned short*)(ws + 8388608);
    unsigned short* WT  = (unsigned short*)(ws + 41943040);  // [640][512]
    unsigned short* xb  = (unsigned short*)(ws + 42598400);
    unsigned short* Pb  = (unsigned short*)(ws + 41943040);  // overlaps WT+xb

    xcvt<<<16384, 256, 0, stream>>>(xf, xb);                 // 16.7M elems
    wtrans_all<<<1280, 256, 0, stream>>>(wq, wk, wv, WT);    // all 640 rows
    qkv<<<dim3(256, 5), 256, 0, stream>>>(xb, WT, bq, bk, bv, qb, kb, vTb);
    scores<<<dim3(64, 32), 256, 0, stream>>>(qb, kb, Pb);
    pv<<<1024, 256, 0, stream>>>(Pb, vTb, xf, out);
}

// Round 7
// 279.188 us; speedup vs baseline: 1.1906x; 1.1906x over previous
//
#include <hip/hip_runtime.h>
#include <stdint.h>

// SelfAttentionLayer: x [32,32,32,512] fp32 -> out fp32 same shape
#define B_ 32
#define N_ 1024   // tokens per batch (H*W)
#define C_ 512
#define D_ 64     // DQK

typedef __attribute__((ext_vector_type(8))) __bf16 bf8;   // MFMA A/B frag (4 VGPRs)
typedef __attribute__((ext_vector_type(4))) float f32x4;  // MFMA C/D frag

typedef const __attribute__((address_space(1))) void* gp_t;
typedef __attribute__((address_space(3))) void* lp_t;

__device__ inline void g2l16(const void* g, void* l) {
    // async global->LDS, 16B/lane; LDS dest = uniform base + lane*16
    __builtin_amdgcn_global_load_lds((gp_t)g, (lp_t)l, 16, 0, 0);
}

__device__ inline float b2f(unsigned short u) {
    return __uint_as_float(((unsigned)u) << 16);
}
__device__ inline unsigned short f2b(float f) {   // f32 -> bf16 bits, RNE
    unsigned u = __float_as_uint(f);
    u += 0x7FFF + ((u >> 16) & 1);
    return (unsigned short)(u >> 16);
}

#define MFMA16(a, b, c) __builtin_amdgcn_mfma_f32_16x16x32_bf16((a), (b), (c), 0, 0, 0)

// fragment loads from a staged (frag-order) 128x64 tile pair
__device__ __forceinline__ void ld_frags(const unsigned short* As, const unsigned short* Bs,
                                         int wm, int wn, int lane,
                                         bf8 (&a)[2][4], bf8 (&bb)[2][4]) {
    #pragma unroll
    for (int kq = 0; kq < 2; ++kq) {
        #pragma unroll
        for (int ti = 0; ti < 4; ++ti)
            a[kq][ti] = *(const bf8*)&As[((wm * 4 + ti) * 2 + kq) * 512 + lane * 8];
        #pragma unroll
        for (int tj = 0; tj < 4; ++tj)
            bb[kq][tj] = *(const bf8*)&Bs[((wn * 4 + tj) * 2 + kq) * 512 + lane * 8];
    }
}

__device__ __forceinline__ void do_mfma(const bf8 (&a)[2][4], const bf8 (&bb)[2][4],
                                        f32x4 (&acc)[4][4]) {
    #pragma unroll
    for (int kq = 0; kq < 2; ++kq)
        #pragma unroll
        for (int ti = 0; ti < 4; ++ti)
            #pragma unroll
            for (int tj = 0; tj < 4; ++tj)
                acc[ti][tj] = MFMA16(a[kq][ti], bb[kq][tj], acc[ti][tj]);
}

// ---------------------------------------------------------------------------
// Kernel 0: x fp32 -> bf16 (so qkv can stage via global_load_lds)
// ---------------------------------------------------------------------------
__global__ __launch_bounds__(256) void xcvt(const float* __restrict__ x,
                                            unsigned short* __restrict__ xb) {
    int i = blockIdx.x * 256 + threadIdx.x;      // quad index, exact grid
    float4 f = ((const float4*)x)[i];
    ushort4 o;
    o.x = f2b(f.x); o.y = f2b(f.y); o.z = f2b(f.z); o.w = f2b(f.w);
    ((ushort4*)xb)[i] = o;
}

// ---------------------------------------------------------------------------
// Kernel 0b: weight transpose + cvt into concatenated WT[640][512] bf16.
// ---------------------------------------------------------------------------
__global__ __launch_bounds__(256) void wtrans_all(
    const float* __restrict__ wq, const float* __restrict__ wk,
    const float* __restrict__ wv, unsigned short* __restrict__ wt)
{
    int t = blockIdx.x * 256 + threadIdx.x;      // output-linear, exact grid (640*512)
    int co = t >> 9;          // /512
    int ci = t & 511;
    const float* src;
    int col, cout;
    if (co < 64)       { src = wq; col = co;       cout = 64;  }
    else if (co < 128) { src = wk; col = co - 64;  cout = 64;  }
    else               { src = wv; col = co - 128; cout = 512; }
    wt[t] = f2b(src[(size_t)ci * cout + col]);
}

// ---------------------------------------------------------------------------
// Kernel 1: QKV projection GEMM. [32768,512]bf16 @ WT[640,512]^T.
// 2-deep counted-vmcnt pipeline (round-2 structure).
// NEW: XCD-grouped flat grid (1280 blocks): xcd = f&7; each XCD owns 32
// consecutive rb panels x all 5 cb.  Consecutive blocks on an XCD share the
// same 128 KB xb row-panel -> fetched once into that XCD's L2 instead of 5x
// scattered.  WT (640 KB) stays L2-resident.
// ---------------------------------------------------------------------------
__global__ __launch_bounds__(256) void qkv(
    const unsigned short* __restrict__ xb,
    const unsigned short* __restrict__ WT,
    const float* __restrict__ bq, const float* __restrict__ bk,
    const float* __restrict__ bv,
    unsigned short* __restrict__ q, unsigned short* __restrict__ k,
    unsigned short* __restrict__ vT)
{
    // XCD-grouped decode: f&7 = XCD (dispatch round-robin).
    const int f_  = blockIdx.x;
    const int xcd = f_ & 7;
    const int s_  = f_ >> 3;          // 0..159 slot within XCD
    const int rb  = xcd * 32 + s_ / 5;    // row-tile 0..255 (contig per XCD)
    const int cb  = s_ % 5;               // 5 col-blocks share one rb panel

    const int tid = threadIdx.x;
    const int lane = tid & 63;
    const int wave = tid >> 6;
    const int wm = wave >> 1, wn = wave & 1;
    const int lr = lane & 15;     // frag row/col within 16
    const int lk = lane >> 4;     // k-octet 0..3

    __shared__ unsigned short SM[32768];      // 64 KB: As[2][8192] | Bs[2][8192]
    unsigned short* TB = SM;                  // aliased transpose buf 128x132 (16896)

    const int row0 = rb * 128;
    const int col0 = cb * 128;                // within [640]

    f32x4 zero4 = {0.f, 0.f, 0.f, 0.f};
    f32x4 acc[4][4];
    #pragma unroll
    for (int i = 0; i < 4; ++i)
        #pragma unroll
        for (int j = 0; j < 4; ++j) acc[i][j] = zero4;

    auto stage = [&](int buf, int kk) {       // 8 loads/wave
        unsigned short* As = SM + buf * 8192;
        unsigned short* Bs = SM + 16384 + buf * 8192;
        #pragma unroll
        for (int i = 0; i < 4; ++i) {          // 16 frags each for A and B
            int f = wave * 4 + i;
            int t = f >> 1, kq = f & 1;
            g2l16(xb + (size_t)(row0 + t * 16 + lr) * C_ + kk + kq * 32 + lk * 8,
                  &As[f * 512]);
            g2l16(WT + (size_t)(col0 + t * 16 + lr) * C_ + kk + kq * 32 + lk * 8,
                  &Bs[f * 512]);
        }
    };

    stage(0, 0);
    stage(1, 64);
    int cur = 0;
    for (int t = 0; t < 6; ++t) {             // steady state: tiles 0..5
        asm volatile("s_waitcnt vmcnt(8)" ::: "memory");   // tile t landed
        __builtin_amdgcn_s_barrier();
        bf8 a[2][4], bb[2][4];
        ld_frags(SM + cur * 8192, SM + 16384 + cur * 8192, wm, wn, lane, a, bb);
        asm volatile("s_waitcnt lgkmcnt(0)" ::: "memory"); // my reads done
        __builtin_amdgcn_s_barrier();                       // everyone's reads done
        stage(cur, (t + 2) * 64);             // reuse buffer for tile t+2
        do_mfma(a, bb, acc);
        cur ^= 1;
    }
    {   // tile 6: wait oldest 8, tile 7 still in flight
        asm volatile("s_waitcnt vmcnt(8)" ::: "memory");
        __builtin_amdgcn_s_barrier();
        bf8 a[2][4], bb[2][4];
        ld_frags(SM + cur * 8192, SM + 16384 + cur * 8192, wm, wn, lane, a, bb);
        do_mfma(a, bb, acc);
        cur ^= 1;
    }
    {   // tile 7: final drain
        asm volatile("s_waitcnt vmcnt(0)" ::: "memory");
        __builtin_amdgcn_s_barrier();
        bf8 a[2][4], bb[2][4];
        ld_frags(SM + cur * 8192, SM + 16384 + cur * 8192, wm, wn, lane, a, bb);
        do_mfma(a, bb, acc);
    }

    if (cb == 0) {
        // wn==0 waves own cols 0..63 (-> q), wn==1 own cols 64..127 (-> k)
        unsigned short* outp = (wn == 0) ? q : k;
        const float* bias = (wn == 0) ? bq : bk;
        #pragma unroll
        for (int ti = 0; ti < 4; ++ti)
            #pragma unroll
            for (int tj = 0; tj < 4; ++tj) {
                int col = tj * 16 + lr;           // 0..63 within q or k
                float bi = bias[col];
                #pragma unroll
                for (int r = 0; r < 4; ++r) {
                    int row = row0 + wm * 64 + ti * 16 + lk * 4 + r;
                    outp[(size_t)row * D_ + col] = f2b(acc[ti][tj][r] + bi);
                }
            }
    } else {
        const int colv = (cb - 1) * 128;          // v col base (0..511)
        __syncthreads();                          // all frag reads done; TB aliases SM
        #pragma unroll
        for (int ti = 0; ti < 4; ++ti)
            #pragma unroll
            for (int tj = 0; tj < 4; ++tj) {
                int c = wn * 64 + tj * 16 + lr;   // 0..127 within block
                float bi = bv[colv + c];
                int tok = wm * 64 + ti * 16 + lk * 4;
                ushort4 o;
                o.x = f2b(acc[ti][tj][0] + bi);
                o.y = f2b(acc[ti][tj][1] + bi);
                o.z = f2b(acc[ti][tj][2] + bi);
                o.w = f2b(acc[ti][tj][3] + bi);
                *(ushort4*)&TB[c * 132 + tok] = o;
            }
        __syncthreads();
        const int b  = row0 >> 10;
        const int n0 = row0 & 1023;
        #pragma unroll
        for (int i = 0; i < 16; ++i) {
            int idx = tid + 256 * i;              // 0..4095
            int c = idx >> 5, ch = idx & 31;
            ushort4 t4 = *(const ushort4*)&TB[c * 132 + ch * 4];
            *(ushort4*)&vT[((size_t)(b * C_ + colv + c)) * N_ + n0 + ch * 4] = t4;
        }
    }
}

// ---------------------------------------------------------------------------
// Kernel 2: scores + softmax -> P bf16 [b][n][m].
// NEW: XCD-grouped flat grid (2048 blocks): each batch's 64 q-tiles land on
// one XCD -> per-batch q/k panels (256 KB) stay L2-resident.
// ---------------------------------------------------------------------------
#define SLD 1032   // S leading dim (shorts), pad 8 to break 2048B bank period
__global__ __launch_bounds__(256) void scores(
    const unsigned short* __restrict__ q,
    const unsigned short* __restrict__ k,
    unsigned short* __restrict__ P)
{
    const int f_  = blockIdx.x;
    const int xcd = f_ & 7;
    const int s_  = f_ >> 3;              // 0..255 slot within XCD
    const int b   = xcd * 4 + (s_ >> 6);  // batch (same-b => same xcd)
    const int qt  = s_ & 63;              // q-tile within batch

    const int tid = threadIdx.x, lane = tid & 63, wave = tid >> 6;
    const int lr = lane & 15, lk = lane >> 4;
    __shared__ unsigned short S[16 * SLD];      // bf16 scores, 33 KB

    const int n0 = qt * 16;
    const unsigned short* qrow = q + (size_t)(b * N_ + n0 + lr) * D_ + lk * 8;
    bf8 qa0 = *(const bf8*)(qrow);
    bf8 qa1 = *(const bf8*)(qrow + 32);

    const int m0w = wave * 256;
    #pragma unroll 4
    for (int mt = 0; mt < 16; ++mt) {
        int m = m0w + mt * 16;
        const unsigned short* krow = k + (size_t)(b * N_ + m + lr) * D_ + lk * 8;
        bf8 kb0 = *(const bf8*)(krow);
        bf8 kb1 = *(const bf8*)(krow + 32);
        f32x4 s = {0.f, 0.f, 0.f, 0.f};
        s = MFMA16(qa0, kb0, s);
        s = MFMA16(qa1, kb1, s);
        #pragma unroll
        for (int r = 0; r < 4; ++r)
            S[(lk * 4 + r) * SLD + m + lr] = f2b(s[r] * 0.125f);  // 1/sqrt(64)
    }
    __syncthreads();

    #pragma unroll
    for (int rr4 = 0; rr4 < 4; ++rr4) {
        int rr = wave * 4 + rr4;
        float vals[16];
        float mx = -1e30f;
        #pragma unroll
        for (int j = 0; j < 16; ++j) {
            vals[j] = b2f(S[rr * SLD + j * 64 + lane]);
            mx = fmaxf(mx, vals[j]);
        }
        #pragma unroll
        for (int off = 32; off; off >>= 1) mx = fmaxf(mx, __shfl_xor(mx, off));
        float sum = 0.f;
        #pragma unroll
        for (int j = 0; j < 16; ++j) { vals[j] = __expf(vals[j] - mx); sum += vals[j]; }
        #pragma unroll
        for (int off = 32; off; off >>= 1) sum += __shfl_xor(sum, off);
        float inv = 1.f / sum;
        unsigned short* pp = P + (size_t)(b * N_ + n0 + rr) * N_;
        #pragma unroll
        for (int j = 0; j < 16; ++j) pp[j * 64 + lane] = f2b(vals[j] * inv);
    }
}

// ---------------------------------------------------------------------------
// Kernel 3: O = P @ V + x (residual), fp32 out. Per-batch GEMM M=1024 N=512
// K=1024. Block tile 128x128, waves 2x2, BK=64.  2-deep counted-vmcnt
// pipeline.  Flat 1024-grid with XCD-bound batch placement (round-4
// verified: FETCH 196->82 MB).
// ---------------------------------------------------------------------------
__global__ __launch_bounds__(256) void pv(
    const unsigned short* __restrict__ P,
    const unsigned short* __restrict__ vT,
    const float* __restrict__ x,
    float* __restrict__ out)
{
    // XCD-bound swizzle: xcd = f&7 (dispatch round-robin), 4 batches/XCD.
    const int f_   = blockIdx.x;
    const int xcd  = f_ & 7;
    const int s_   = f_ >> 3;            // 0..127 slot within XCD
    const int b    = xcd * 4 + (s_ >> 5);    // batch (same-b => same xcd)
    const int w_   = s_ & 31;            // 0..31 tile within batch
    const int m0   = (w_ & 7) * 128;
    const int c0   = (w_ >> 3) * 128;

    const int tid = threadIdx.x, lane = tid & 63, wave = tid >> 6;
    const int wm = wave >> 1, wn = wave & 1;
    const int lr = lane & 15, lk = lane >> 4;

    __shared__ unsigned short As[2][8192];   // P frags, double-buffered
    __shared__ unsigned short Bs[2][8192];   // V frags, double-buffered

    f32x4 zero4 = {0.f, 0.f, 0.f, 0.f};
    f32x4 acc[4][4];
    #pragma unroll
    for (int i = 0; i < 4; ++i)
        #pragma unroll
        for (int j = 0; j < 4; ++j) acc[i][j] = zero4;

    const unsigned short* Pb = P  + (size_t)b * N_ * N_;
    const unsigned short* Vb = vT + (size_t)b * C_ * N_;

    auto stage = [&](int buf, int kk) {       // 8 loads/wave
        #pragma unroll
        for (int i = 0; i < 4; ++i) {
            int f = wave * 4 + i;
            int t = f >> 1, kq = f & 1;
            g2l16(Pb + (size_t)(m0 + t * 16 + lr) * N_ + kk + kq * 32 + lk * 8,
                  &As[buf][f * 512]);
            g2l16(Vb + (size_t)(c0 + t * 16 + lr) * N_ + kk + kq * 32 + lk * 8,
                  &Bs[buf][f * 512]);
        }
    };

    stage(0, 0);
    stage(1, 64);
    int cur = 0;
    for (int t = 0; t < 14; ++t) {            // steady state: tiles 0..13
        asm volatile("s_waitcnt vmcnt(8)" ::: "memory");   // tile t landed
        __builtin_amdgcn_s_barrier();
        bf8 a[2][4], bb[2][4];
        ld_frags(&As[cur][0], &Bs[cur][0], wm, wn, lane, a, bb);
        asm volatile("s_waitcnt lgkmcnt(0)" ::: "memory"); // my reads done
        __builtin_amdgcn_s_barrier();                       // everyone's reads done
        stage(cur, (t + 2) * 64);             // reuse buffer for tile t+2
        do_mfma(a, bb, acc);
        cur ^= 1;
    }
    {   // tile 14: wait oldest 8, tile 15 still in flight
        asm volatile("s_waitcnt vmcnt(8)" ::: "memory");
        __builtin_amdgcn_s_barrier();
        bf8 a[2][4], bb[2][4];
        ld_frags(&As[cur][0], &Bs[cur][0], wm, wn, lane, a, bb);
        do_mfma(a, bb, acc);
        cur ^= 1;
    }
    {   // tile 15: final drain
        asm volatile("s_waitcnt vmcnt(0)" ::: "memory");
        __builtin_amdgcn_s_barrier();
        bf8 a[2][4], bb[2][4];
        ld_frags(&As[cur][0], &Bs[cur][0], wm, wn, lane, a, bb);
        do_mfma(a, bb, acc);
    }

    #pragma unroll
    for (int ti = 0; ti < 4; ++ti)
        #pragma unroll
        for (int tj = 0; tj < 4; ++tj) {
            int col = c0 + wn * 64 + tj * 16 + lr;
            #pragma unroll
            for (int r = 0; r < 4; ++r) {
                int row = m0 + wm * 64 + ti * 16 + lk * 4 + r;
                size_t idx = (size_t)(b * N_ + row) * C_ + col;
                out[idx] = acc[ti][tj][r] + x[idx];
            }
        }
}

// ---------------------------------------------------------------------------
extern "C" void kernel_launch(void* const* d_in, const int* in_sizes, int n_in,
                              void* d_out, int out_size, void* d_ws, size_t ws_size,
                              hipStream_t stream) {
    (void)in_sizes; (void)n_in; (void)out_size; (void)ws_size;
    const float* xf = (const float*)d_in[0];
    const float* wq = (const float*)d_in[1];
    const float* bq = (const float*)d_in[2];
    const float* wk = (const float*)d_in[3];
    const float* bk = (const float*)d_in[4];
    const float* wv = (const float*)d_in[5];
    const float* bv = (const float*)d_in[6];
    float* out = (float*)d_out;

    // workspace layout (bytes), total needed ~109 MB:
    //   q [0,4MB) | k [4MB,8MB) | vT [8MB,40MB)
    //   WT (655KB) + xb (32MB) in [40MB, 76MB)  -- dead after qkv
    //   P (64MB) aliased over WT+xb region starting 41,943,040
    char* ws = (char*)d_ws;
    unsigned short* qb  = (unsigned short*)(ws);
    unsigned short* kb  = (unsigned short*)(ws + 4194304);
    unsigned short* vTb = (unsigned short*)(ws + 8388608);
    unsigned short* WT  = (unsigned short*)(ws + 41943040);  // [640][512]
    unsigned short* xb  = (unsigned short*)(ws + 42598400);
    unsigned short* Pb  = (unsigned short*)(ws + 41943040);  // overlaps WT+xb

    xcvt<<<16384, 256, 0, stream>>>(xf, xb);                 // 16.7M elems
    wtrans_all<<<1280, 256, 0, stream>>>(wq, wk, wv, WT);    // all 640 rows
    qkv<<<1280, 256, 0, stream>>>(xb, WT, bq, bk, bv, qb, kb, vTb);
    scores<<<2048, 256, 0, stream>>>(qb, kb, Pb);
    pv<<<1024, 256, 0, stream>>>(Pb, vTb, xf, out);
}

// Round 8
// 271.735 us; speedup vs baseline: 1.2233x; 1.0274x over previous
//
#include <hip/hip_runtime.h>
#include <stdint.h>

// SelfAttentionLayer: x [32,32,32,512] fp32 -> out fp32 same shape
#define B_ 32
#define N_ 1024   // tokens per batch (H*W)
#define C_ 512
#define D_ 64     // DQK

typedef __attribute__((ext_vector_type(8))) __bf16 bf8;   // MFMA A/B frag (4 VGPRs)
typedef __attribute__((ext_vector_type(4))) float f32x4;  // MFMA C/D frag

typedef const __attribute__((address_space(1))) void* gp_t;
typedef __attribute__((address_space(3))) void* lp_t;

__device__ inline void g2l16(const void* g, void* l) {
    // async global->LDS, 16B/lane; LDS dest = uniform base + lane*16
    __builtin_amdgcn_global_load_lds((gp_t)g, (lp_t)l, 16, 0, 0);
}

__device__ inline float b2f(unsigned short u) {
    return __uint_as_float(((unsigned)u) << 16);
}
__device__ inline unsigned short f2b(float f) {   // f32 -> bf16 bits, RNE
    unsigned u = __float_as_uint(f);
    u += 0x7FFF + ((u >> 16) & 1);
    return (unsigned short)(u >> 16);
}

#define MFMA16(a, b, c) __builtin_amdgcn_mfma_f32_16x16x32_bf16((a), (b), (c), 0, 0, 0)

// fragment loads from a staged (frag-order) 128x64 tile pair
__device__ __forceinline__ void ld_frags(const unsigned short* As, const unsigned short* Bs,
                                         int wm, int wn, int lane,
                                         bf8 (&a)[2][4], bf8 (&bb)[2][4]) {
    #pragma unroll
    for (int kq = 0; kq < 2; ++kq) {
        #pragma unroll
        for (int ti = 0; ti < 4; ++ti)
            a[kq][ti] = *(const bf8*)&As[((wm * 4 + ti) * 2 + kq) * 512 + lane * 8];
        #pragma unroll
        for (int tj = 0; tj < 4; ++tj)
            bb[kq][tj] = *(const bf8*)&Bs[((wn * 4 + tj) * 2 + kq) * 512 + lane * 8];
    }
}

__device__ __forceinline__ void do_mfma(const bf8 (&a)[2][4], const bf8 (&bb)[2][4],
                                        f32x4 (&acc)[4][4]) {
    #pragma unroll
    for (int kq = 0; kq < 2; ++kq)
        #pragma unroll
        for (int ti = 0; ti < 4; ++ti)
            #pragma unroll
            for (int tj = 0; tj < 4; ++tj)
                acc[ti][tj] = MFMA16(a[kq][ti], bb[kq][tj], acc[ti][tj]);
}

// ---------------------------------------------------------------------------
// Kernel 0: x fp32 -> bf16 (so qkv can stage via global_load_lds)
// ---------------------------------------------------------------------------
__global__ __launch_bounds__(256) void xcvt(const float* __restrict__ x,
                                            unsigned short* __restrict__ xb) {
    int i = blockIdx.x * 256 + threadIdx.x;      // quad index, exact grid
    float4 f = ((const float4*)x)[i];
    ushort4 o;
    o.x = f2b(f.x); o.y = f2b(f.y); o.z = f2b(f.z); o.w = f2b(f.w);
    ((ushort4*)xb)[i] = o;
}

// ---------------------------------------------------------------------------
// Kernel 0b: weight transpose + cvt into concatenated WT[640][512] bf16.
// ---------------------------------------------------------------------------
__global__ __launch_bounds__(256) void wtrans_all(
    const float* __restrict__ wq, const float* __restrict__ wk,
    const float* __restrict__ wv, unsigned short* __restrict__ wt)
{
    int t = blockIdx.x * 256 + threadIdx.x;      // output-linear, exact grid (640*512)
    int co = t >> 9;          // /512
    int ci = t & 511;
    const float* src;
    int col, cout;
    if (co < 64)       { src = wq; col = co;       cout = 64;  }
    else if (co < 128) { src = wk; col = co - 64;  cout = 64;  }
    else               { src = wv; col = co - 128; cout = 512; }
    wt[t] = f2b(src[(size_t)ci * cout + col]);
}

// ---------------------------------------------------------------------------
// Kernel 1: QKV projection GEMM. [32768,512]bf16 @ WT[640,512]^T.
// 2-deep counted-vmcnt pipeline, XCD-grouped flat grid (unchanged, r7).
// ---------------------------------------------------------------------------
__global__ __launch_bounds__(256) void qkv(
    const unsigned short* __restrict__ xb,
    const unsigned short* __restrict__ WT,
    const float* __restrict__ bq, const float* __restrict__ bk,
    const float* __restrict__ bv,
    unsigned short* __restrict__ q, unsigned short* __restrict__ k,
    unsigned short* __restrict__ vT)
{
    // XCD-grouped decode: f&7 = XCD (dispatch round-robin).
    const int f_  = blockIdx.x;
    const int xcd = f_ & 7;
    const int s_  = f_ >> 3;          // 0..159 slot within XCD
    const int rb  = xcd * 32 + s_ / 5;    // row-tile 0..255 (contig per XCD)
    const int cb  = s_ % 5;               // 5 col-blocks share one rb panel

    const int tid = threadIdx.x;
    const int lane = tid & 63;
    const int wave = tid >> 6;
    const int wm = wave >> 1, wn = wave & 1;
    const int lr = lane & 15;     // frag row/col within 16
    const int lk = lane >> 4;     // k-octet 0..3

    __shared__ unsigned short SM[32768];      // 64 KB: As[2][8192] | Bs[2][8192]
    unsigned short* TB = SM;                  // aliased transpose buf 128x132 (16896)

    const int row0 = rb * 128;
    const int col0 = cb * 128;                // within [640]

    f32x4 zero4 = {0.f, 0.f, 0.f, 0.f};
    f32x4 acc[4][4];
    #pragma unroll
    for (int i = 0; i < 4; ++i)
        #pragma unroll
        for (int j = 0; j < 4; ++j) acc[i][j] = zero4;

    auto stage = [&](int buf, int kk) {       // 8 loads/wave
        unsigned short* As = SM + buf * 8192;
        unsigned short* Bs = SM + 16384 + buf * 8192;
        #pragma unroll
        for (int i = 0; i < 4; ++i) {          // 16 frags each for A and B
            int f = wave * 4 + i;
            int t = f >> 1, kq = f & 1;
            g2l16(xb + (size_t)(row0 + t * 16 + lr) * C_ + kk + kq * 32 + lk * 8,
                  &As[f * 512]);
            g2l16(WT + (size_t)(col0 + t * 16 + lr) * C_ + kk + kq * 32 + lk * 8,
                  &Bs[f * 512]);
        }
    };

    stage(0, 0);
    stage(1, 64);
    int cur = 0;
    for (int t = 0; t < 6; ++t) {             // steady state: tiles 0..5
        asm volatile("s_waitcnt vmcnt(8)" ::: "memory");   // tile t landed
        __builtin_amdgcn_s_barrier();
        bf8 a[2][4], bb[2][4];
        ld_frags(SM + cur * 8192, SM + 16384 + cur * 8192, wm, wn, lane, a, bb);
        asm volatile("s_waitcnt lgkmcnt(0)" ::: "memory"); // my reads done
        __builtin_amdgcn_s_barrier();                       // everyone's reads done
        stage(cur, (t + 2) * 64);             // reuse buffer for tile t+2
        do_mfma(a, bb, acc);
        cur ^= 1;
    }
    {   // tile 6: wait oldest 8, tile 7 still in flight
        asm volatile("s_waitcnt vmcnt(8)" ::: "memory");
        __builtin_amdgcn_s_barrier();
        bf8 a[2][4], bb[2][4];
        ld_frags(SM + cur * 8192, SM + 16384 + cur * 8192, wm, wn, lane, a, bb);
        do_mfma(a, bb, acc);
        cur ^= 1;
    }
    {   // tile 7: final drain
        asm volatile("s_waitcnt vmcnt(0)" ::: "memory");
        __builtin_amdgcn_s_barrier();
        bf8 a[2][4], bb[2][4];
        ld_frags(SM + cur * 8192, SM + 16384 + cur * 8192, wm, wn, lane, a, bb);
        do_mfma(a, bb, acc);
    }

    if (cb == 0) {
        // wn==0 waves own cols 0..63 (-> q), wn==1 own cols 64..127 (-> k)
        unsigned short* outp = (wn == 0) ? q : k;
        const float* bias = (wn == 0) ? bq : bk;
        #pragma unroll
        for (int ti = 0; ti < 4; ++ti)
            #pragma unroll
            for (int tj = 0; tj < 4; ++tj) {
                int col = tj * 16 + lr;           // 0..63 within q or k
                float bi = bias[col];
                #pragma unroll
                for (int r = 0; r < 4; ++r) {
                    int row = row0 + wm * 64 + ti * 16 + lk * 4 + r;
                    outp[(size_t)row * D_ + col] = f2b(acc[ti][tj][r] + bi);
                }
            }
    } else {
        const int colv = (cb - 1) * 128;          // v col base (0..511)
        __syncthreads();                          // all frag reads done; TB aliases SM
        #pragma unroll
        for (int ti = 0; ti < 4; ++ti)
            #pragma unroll
            for (int tj = 0; tj < 4; ++tj) {
                int c = wn * 64 + tj * 16 + lr;   // 0..127 within block
                float bi = bv[colv + c];
                int tok = wm * 64 + ti * 16 + lk * 4;
                ushort4 o;
                o.x = f2b(acc[ti][tj][0] + bi);
                o.y = f2b(acc[ti][tj][1] + bi);
                o.z = f2b(acc[ti][tj][2] + bi);
                o.w = f2b(acc[ti][tj][3] + bi);
                *(ushort4*)&TB[c * 132 + tok] = o;
            }
        __syncthreads();
        const int b  = row0 >> 10;
        const int n0 = row0 & 1023;
        #pragma unroll
        for (int i = 0; i < 16; ++i) {
            int idx = tid + 256 * i;              // 0..4095
            int c = idx >> 5, ch = idx & 31;
            ushort4 t4 = *(const ushort4*)&TB[c * 132 + ch * 4];
            *(ushort4*)&vT[((size_t)(b * C_ + colv + c)) * N_ + n0 + ch * 4] = t4;
        }
    }
}

// ---------------------------------------------------------------------------
// Kernel 2: scores + softmax -> P bf16 [b][n][m].  (unchanged, r7)
// ---------------------------------------------------------------------------
#define SLD 1032   // S leading dim (shorts), pad 8 to break 2048B bank period
__global__ __launch_bounds__(256) void scores(
    const unsigned short* __restrict__ q,
    const unsigned short* __restrict__ k,
    unsigned short* __restrict__ P)
{
    const int f_  = blockIdx.x;
    const int xcd = f_ & 7;
    const int s_  = f_ >> 3;              // 0..255 slot within XCD
    const int b   = xcd * 4 + (s_ >> 6);  // batch (same-b => same xcd)
    const int qt  = s_ & 63;              // q-tile within batch

    const int tid = threadIdx.x, lane = tid & 63, wave = tid >> 6;
    const int lr = lane & 15, lk = lane >> 4;
    __shared__ unsigned short S[16 * SLD];      // bf16 scores, 33 KB

    const int n0 = qt * 16;
    const unsigned short* qrow = q + (size_t)(b * N_ + n0 + lr) * D_ + lk * 8;
    bf8 qa0 = *(const bf8*)(qrow);
    bf8 qa1 = *(const bf8*)(qrow + 32);

    const int m0w = wave * 256;
    #pragma unroll 4
    for (int mt = 0; mt < 16; ++mt) {
        int m = m0w + mt * 16;
        const unsigned short* krow = k + (size_t)(b * N_ + m + lr) * D_ + lk * 8;
        bf8 kb0 = *(const bf8*)(krow);
        bf8 kb1 = *(const bf8*)(krow + 32);
        f32x4 s = {0.f, 0.f, 0.f, 0.f};
        s = MFMA16(qa0, kb0, s);
        s = MFMA16(qa1, kb1, s);
        #pragma unroll
        for (int r = 0; r < 4; ++r)
            S[(lk * 4 + r) * SLD + m + lr] = f2b(s[r] * 0.125f);  // 1/sqrt(64)
    }
    __syncthreads();

    #pragma unroll
    for (int rr4 = 0; rr4 < 4; ++rr4) {
        int rr = wave * 4 + rr4;
        float vals[16];
        float mx = -1e30f;
        #pragma unroll
        for (int j = 0; j < 16; ++j) {
            vals[j] = b2f(S[rr * SLD + j * 64 + lane]);
            mx = fmaxf(mx, vals[j]);
        }
        #pragma unroll
        for (int off = 32; off; off >>= 1) mx = fmaxf(mx, __shfl_xor(mx, off));
        float sum = 0.f;
        #pragma unroll
        for (int j = 0; j < 16; ++j) { vals[j] = __expf(vals[j] - mx); sum += vals[j]; }
        #pragma unroll
        for (int off = 32; off; off >>= 1) sum += __shfl_xor(sum, off);
        float inv = 1.f / sum;
        unsigned short* pp = P + (size_t)(b * N_ + n0 + rr) * N_;
        #pragma unroll
        for (int j = 0; j < 16; ++j) pp[j * 64 + lane] = f2b(vals[j] * inv);
    }
}

// ---------------------------------------------------------------------------
// Kernel 3: O = P @ V + x (residual), fp32 out.  NEW: 256x256 block tile,
// 512 threads (8 waves, 2M x 4N; each wave owns 128x64 out).  BK=64,
// frag-order LDS (conflict-free), global_load_lds staging, 2-deep
// counted-vmcnt pipeline (same verified schedule as before, bigger tile:
// FLOP per staged byte and per LDS-read byte doubles vs 128x128).
// LDS = As[2][32K] + Bs[2][32K] = 128 KB -> 1 block/CU, grid 256 = 1/CU.
// XCD-bound: all 8 tiles of a batch on one XCD.
// ---------------------------------------------------------------------------
__global__ __launch_bounds__(512, 2) void pv(
    const unsigned short* __restrict__ P,
    const unsigned short* __restrict__ vT,
    const float* __restrict__ x,
    float* __restrict__ out)
{
    // 256 blocks: xcd = f&7; 4 batches/XCD x 8 tiles (4M x 2N of 256).
    const int f_   = blockIdx.x;
    const int xcd  = f_ & 7;
    const int s_   = f_ >> 3;             // 0..31 slot within XCD
    const int b    = xcd * 4 + (s_ >> 3); // batch (same-b => same xcd)
    const int w_   = s_ & 7;              // tile within batch
    const int m0   = (w_ & 3) * 256;
    const int c0   = (w_ >> 2) * 256;

    const int tid = threadIdx.x, lane = tid & 63, wave = tid >> 6;  // 8 waves
    const int wm = wave >> 2;             // 0..1 -> rows wm*128
    const int wn = wave & 3;              // 0..3 -> cols wn*64
    const int lr = lane & 15, lk = lane >> 4;

    __shared__ unsigned short SM[65536];  // 128 KB
    // As[buf] = SM + buf*16384 (32 frags x 512 shorts); Bs[buf] = SM + 32768 + buf*16384

    f32x4 zero4 = {0.f, 0.f, 0.f, 0.f};
    f32x4 acc[8][4];
    #pragma unroll
    for (int i = 0; i < 8; ++i)
        #pragma unroll
        for (int j = 0; j < 4; ++j) acc[i][j] = zero4;

    const unsigned short* Pb = P  + (size_t)b * N_ * N_;
    const unsigned short* Vb = vT + (size_t)b * C_ * N_;

    auto stage = [&](int buf, int kk) {       // 8 loads/thread (4 A + 4 B)
        unsigned short* As = SM + buf * 16384;
        unsigned short* Bs = SM + 32768 + buf * 16384;
        #pragma unroll
        for (int i = 0; i < 4; ++i) {          // 32 frags each for A and B
            int f = wave * 4 + i;              // 0..31
            int t = f >> 1, kq = f & 1;        // row-tile 0..15, k-half
            g2l16(Pb + (size_t)(m0 + t * 16 + lr) * N_ + kk + kq * 32 + lk * 8,
                  &As[f * 512]);
            g2l16(Vb + (size_t)(c0 + t * 16 + lr) * N_ + kk + kq * 32 + lk * 8,
                  &Bs[f * 512]);
        }
    };

    // per-kq fragment read + MFMA (keeps live frags at 12, VGPR ~190)
    auto compute = [&](int buf) {
        const unsigned short* As = SM + buf * 16384;
        const unsigned short* Bs = SM + 32768 + buf * 16384;
        #pragma unroll
        for (int kq = 0; kq < 2; ++kq) {
            bf8 a[8], bb[4];
            #pragma unroll
            for (int ti = 0; ti < 8; ++ti)
                a[ti] = *(const bf8*)&As[((wm * 8 + ti) * 2 + kq) * 512 + lane * 8];
            #pragma unroll
            for (int tj = 0; tj < 4; ++tj)
                bb[tj] = *(const bf8*)&Bs[((wn * 4 + tj) * 2 + kq) * 512 + lane * 8];
            #pragma unroll
            for (int ti = 0; ti < 8; ++ti)
                #pragma unroll
                for (int tj = 0; tj < 4; ++tj)
                    acc[ti][tj] = MFMA16(a[ti], bb[tj], acc[ti][tj]);
        }
    };

    stage(0, 0);
    stage(1, 64);
    int cur = 0;
    for (int t = 0; t < 14; ++t) {            // steady state: tiles 0..13
        asm volatile("s_waitcnt vmcnt(8)" ::: "memory");   // tile t landed
        __builtin_amdgcn_s_barrier();
        compute(cur);
        asm volatile("s_waitcnt lgkmcnt(0)" ::: "memory"); // my reads done
        __builtin_amdgcn_s_barrier();                       // everyone's reads done
        stage(cur, (t + 2) * 64);             // reuse buffer for tile t+2
        cur ^= 1;
    }
    {   // tile 14: wait oldest 8, tile 15 still in flight
        asm volatile("s_waitcnt vmcnt(8)" ::: "memory");
        __builtin_amdgcn_s_barrier();
        compute(cur);
        cur ^= 1;
    }
    {   // tile 15: final drain
        asm volatile("s_waitcnt vmcnt(0)" ::: "memory");
        __builtin_amdgcn_s_barrier();
        compute(cur);
    }

    #pragma unroll
    for (int ti = 0; ti < 8; ++ti)
        #pragma unroll
        for (int tj = 0; tj < 4; ++tj) {
            int col = c0 + wn * 64 + tj * 16 + lr;
            #pragma unroll
            for (int r = 0; r < 4; ++r) {
                int row = m0 + wm * 128 + ti * 16 + lk * 4 + r;
                size_t idx = (size_t)(b * N_ + row) * C_ + col;
                out[idx] = acc[ti][tj][r] + x[idx];
            }
        }
}

// ---------------------------------------------------------------------------
extern "C" void kernel_launch(void* const* d_in, const int* in_sizes, int n_in,
                              void* d_out, int out_size, void* d_ws, size_t ws_size,
                              hipStream_t stream) {
    (void)in_sizes; (void)n_in; (void)out_size; (void)ws_size;
    const float* xf = (const float*)d_in[0];
    const float* wq = (const float*)d_in[1];
    const float* bq = (const float*)d_in[2];
    const float* wk = (const float*)d_in[3];
    const float* bk = (const float*)d_in[4];
    const float* wv = (const float*)d_in[5];
    const float* bv = (const float*)d_in[6];
    float* out = (float*)d_out;

    // workspace layout (bytes), total needed ~109 MB:
    //   q [0,4MB) | k [4MB,8MB) | vT [8MB,40MB)
    //   WT (655KB) + xb (32MB) in [40MB, 76MB)  -- dead after qkv
    //   P (64MB) aliased over WT+xb region starting 41,943,040
    char* ws = (char*)d_ws;
    unsigned short* qb  = (unsigned short*)(ws);
    unsigned short* kb  = (unsigned short*)(ws + 4194304);
    unsigned short* vTb = (unsigned short*)(ws + 8388608);
    unsigned short* WT  = (unsigned short*)(ws + 41943040);  // [640][512]
    unsigned short* xb  = (unsigned short*)(ws + 42598400);
    unsigned short* Pb  = (unsigned short*)(ws + 41943040);  // overlaps WT+xb

    xcvt<<<16384, 256, 0, stream>>>(xf, xb);                 // 16.7M elems
    wtrans_all<<<1280, 256, 0, stream>>>(wq, wk, wv, WT);    // all 640 rows
    qkv<<<1280, 256, 0, stream>>>(xb, WT, bq, bk, bv, qb, kb, vTb);
    scores<<<2048, 256, 0, stream>>>(qb, kb, Pb);
    pv<<<256, 512, 0, stream>>>(Pb, vTb, xf, out);
}

// Round 9
// 265.315 us; speedup vs baseline: 1.2529x; 1.0242x over previous
//
#include <hip/hip_runtime.h>
#include <stdint.h>

// SelfAttentionLayer: x [32,32,32,512] fp32 -> out fp32 same shape
#define B_ 32
#define N_ 1024   // tokens per batch (H*W)
#define C_ 512
#define D_ 64     // DQK

typedef __attribute__((ext_vector_type(8))) __bf16 bf8;   // MFMA A/B frag (4 VGPRs)
typedef __attribute__((ext_vector_type(4))) float f32x4;  // MFMA C/D frag

typedef const __attribute__((address_space(1))) void* gp_t;
typedef __attribute__((address_space(3))) void* lp_t;

__device__ inline void g2l16(const void* g, void* l) {
    // async global->LDS, 16B/lane; LDS dest = uniform base + lane*16
    __builtin_amdgcn_global_load_lds((gp_t)g, (lp_t)l, 16, 0, 0);
}

__device__ inline float b2f(unsigned short u) {
    return __uint_as_float(((unsigned)u) << 16);
}
__device__ inline unsigned short f2b(float f) {   // f32 -> bf16 bits, RNE
    unsigned u = __float_as_uint(f);
    u += 0x7FFF + ((u >> 16) & 1);
    return (unsigned short)(u >> 16);
}

#define MFMA16(a, b, c) __builtin_amdgcn_mfma_f32_16x16x32_bf16((a), (b), (c), 0, 0, 0)

// fragment loads from a staged (frag-order) 128x64 tile pair
__device__ __forceinline__ void ld_frags(const unsigned short* As, const unsigned short* Bs,
                                         int wm, int wn, int lane,
                                         bf8 (&a)[2][4], bf8 (&bb)[2][4]) {
    #pragma unroll
    for (int kq = 0; kq < 2; ++kq) {
        #pragma unroll
        for (int ti = 0; ti < 4; ++ti)
            a[kq][ti] = *(const bf8*)&As[((wm * 4 + ti) * 2 + kq) * 512 + lane * 8];
        #pragma unroll
        for (int tj = 0; tj < 4; ++tj)
            bb[kq][tj] = *(const bf8*)&Bs[((wn * 4 + tj) * 2 + kq) * 512 + lane * 8];
    }
}

__device__ __forceinline__ void do_mfma(const bf8 (&a)[2][4], const bf8 (&bb)[2][4],
                                        f32x4 (&acc)[4][4]) {
    #pragma unroll
    for (int kq = 0; kq < 2; ++kq)
        #pragma unroll
        for (int ti = 0; ti < 4; ++ti)
            #pragma unroll
            for (int tj = 0; tj < 4; ++tj)
                acc[ti][tj] = MFMA16(a[kq][ti], bb[kq][tj], acc[ti][tj]);
}

// ---------------------------------------------------------------------------
// Kernel 0: x fp32 -> bf16 (so qkv can stage via global_load_lds)
// ---------------------------------------------------------------------------
__global__ __launch_bounds__(256) void xcvt(const float* __restrict__ x,
                                            unsigned short* __restrict__ xb) {
    int i = blockIdx.x * 256 + threadIdx.x;      // quad index, exact grid
    float4 f = ((const float4*)x)[i];
    ushort4 o;
    o.x = f2b(f.x); o.y = f2b(f.y); o.z = f2b(f.z); o.w = f2b(f.w);
    ((ushort4*)xb)[i] = o;
}

// ---------------------------------------------------------------------------
// Kernel 0b: weight transpose + cvt into concatenated WT[640][512] bf16.
// ---------------------------------------------------------------------------
__global__ __launch_bounds__(256) void wtrans_all(
    const float* __restrict__ wq, const float* __restrict__ wk,
    const float* __restrict__ wv, unsigned short* __restrict__ wt)
{
    int t = blockIdx.x * 256 + threadIdx.x;      // output-linear, exact grid (640*512)
    int co = t >> 9;          // /512
    int ci = t & 511;
    const float* src;
    int col, cout;
    if (co < 64)       { src = wq; col = co;       cout = 64;  }
    else if (co < 128) { src = wk; col = co - 64;  cout = 64;  }
    else               { src = wv; col = co - 128; cout = 512; }
    wt[t] = f2b(src[(size_t)ci * cout + col]);
}

// ---------------------------------------------------------------------------
// Kernel 1: QKV projection GEMM. [32768,512]bf16 @ WT[640,512]^T.
// 2-deep counted-vmcnt pipeline, XCD-grouped flat grid (unchanged, r7).
// ---------------------------------------------------------------------------
__global__ __launch_bounds__(256) void qkv(
    const unsigned short* __restrict__ xb,
    const unsigned short* __restrict__ WT,
    const float* __restrict__ bq, const float* __restrict__ bk,
    const float* __restrict__ bv,
    unsigned short* __restrict__ q, unsigned short* __restrict__ k,
    unsigned short* __restrict__ vT)
{
    // XCD-grouped decode: f&7 = XCD (dispatch round-robin).
    const int f_  = blockIdx.x;
    const int xcd = f_ & 7;
    const int s_  = f_ >> 3;          // 0..159 slot within XCD
    const int rb  = xcd * 32 + s_ / 5;    // row-tile 0..255 (contig per XCD)
    const int cb  = s_ % 5;               // 5 col-blocks share one rb panel

    const int tid = threadIdx.x;
    const int lane = tid & 63;
    const int wave = tid >> 6;
    const int wm = wave >> 1, wn = wave & 1;
    const int lr = lane & 15;     // frag row/col within 16
    const int lk = lane >> 4;     // k-octet 0..3

    __shared__ unsigned short SM[32768];      // 64 KB: As[2][8192] | Bs[2][8192]
    unsigned short* TB = SM;                  // aliased transpose buf 128x132 (16896)

    const int row0 = rb * 128;
    const int col0 = cb * 128;                // within [640]

    f32x4 zero4 = {0.f, 0.f, 0.f, 0.f};
    f32x4 acc[4][4];
    #pragma unroll
    for (int i = 0; i < 4; ++i)
        #pragma unroll
        for (int j = 0; j < 4; ++j) acc[i][j] = zero4;

    auto stage = [&](int buf, int kk) {       // 8 loads/wave
        unsigned short* As = SM + buf * 8192;
        unsigned short* Bs = SM + 16384 + buf * 8192;
        #pragma unroll
        for (int i = 0; i < 4; ++i) {          // 16 frags each for A and B
            int f = wave * 4 + i;
            int t = f >> 1, kq = f & 1;
            g2l16(xb + (size_t)(row0 + t * 16 + lr) * C_ + kk + kq * 32 + lk * 8,
                  &As[f * 512]);
            g2l16(WT + (size_t)(col0 + t * 16 + lr) * C_ + kk + kq * 32 + lk * 8,
                  &Bs[f * 512]);
        }
    };

    stage(0, 0);
    stage(1, 64);
    int cur = 0;
    for (int t = 0; t < 6; ++t) {             // steady state: tiles 0..5
        asm volatile("s_waitcnt vmcnt(8)" ::: "memory");   // tile t landed
        __builtin_amdgcn_s_barrier();
        bf8 a[2][4], bb[2][4];
        ld_frags(SM + cur * 8192, SM + 16384 + cur * 8192, wm, wn, lane, a, bb);
        asm volatile("s_waitcnt lgkmcnt(0)" ::: "memory"); // my reads done
        __builtin_amdgcn_s_barrier();                       // everyone's reads done
        stage(cur, (t + 2) * 64);             // reuse buffer for tile t+2
        do_mfma(a, bb, acc);
        cur ^= 1;
    }
    {   // tile 6: wait oldest 8, tile 7 still in flight
        asm volatile("s_waitcnt vmcnt(8)" ::: "memory");
        __builtin_amdgcn_s_barrier();
        bf8 a[2][4], bb[2][4];
        ld_frags(SM + cur * 8192, SM + 16384 + cur * 8192, wm, wn, lane, a, bb);
        do_mfma(a, bb, acc);
        cur ^= 1;
    }
    {   // tile 7: final drain
        asm volatile("s_waitcnt vmcnt(0)" ::: "memory");
        __builtin_amdgcn_s_barrier();
        bf8 a[2][4], bb[2][4];
        ld_frags(SM + cur * 8192, SM + 16384 + cur * 8192, wm, wn, lane, a, bb);
        do_mfma(a, bb, acc);
    }

    if (cb == 0) {
        // wn==0 waves own cols 0..63 (-> q), wn==1 own cols 64..127 (-> k)
        unsigned short* outp = (wn == 0) ? q : k;
        const float* bias = (wn == 0) ? bq : bk;
        #pragma unroll
        for (int ti = 0; ti < 4; ++ti)
            #pragma unroll
            for (int tj = 0; tj < 4; ++tj) {
                int col = tj * 16 + lr;           // 0..63 within q or k
                float bi = bias[col];
                #pragma unroll
                for (int r = 0; r < 4; ++r) {
                    int row = row0 + wm * 64 + ti * 16 + lk * 4 + r;
                    outp[(size_t)row * D_ + col] = f2b(acc[ti][tj][r] + bi);
                }
            }
    } else {
        const int colv = (cb - 1) * 128;          // v col base (0..511)
        __syncthreads();                          // all frag reads done; TB aliases SM
        #pragma unroll
        for (int ti = 0; ti < 4; ++ti)
            #pragma unroll
            for (int tj = 0; tj < 4; ++tj) {
                int c = wn * 64 + tj * 16 + lr;   // 0..127 within block
                float bi = bv[colv + c];
                int tok = wm * 64 + ti * 16 + lk * 4;
                ushort4 o;
                o.x = f2b(acc[ti][tj][0] + bi);
                o.y = f2b(acc[ti][tj][1] + bi);
                o.z = f2b(acc[ti][tj][2] + bi);
                o.w = f2b(acc[ti][tj][3] + bi);
                *(ushort4*)&TB[c * 132 + tok] = o;
            }
        __syncthreads();
        const int b  = row0 >> 10;
        const int n0 = row0 & 1023;
        #pragma unroll
        for (int i = 0; i < 16; ++i) {
            int idx = tid + 256 * i;              // 0..4095
            int c = idx >> 5, ch = idx & 31;
            ushort4 t4 = *(const ushort4*)&TB[c * 132 + ch * 4];
            *(ushort4*)&vT[((size_t)(b * C_ + colv + c)) * N_ + n0 + ch * 4] = t4;
        }
    }
}

// ---------------------------------------------------------------------------
// Kernel 2: scores + softmax -> P bf16 [b][n][m].  (unchanged, r7)
// ---------------------------------------------------------------------------
#define SLD 1032   // S leading dim (shorts), pad 8 to break 2048B bank period
__global__ __launch_bounds__(256) void scores(
    const unsigned short* __restrict__ q,
    const unsigned short* __restrict__ k,
    unsigned short* __restrict__ P)
{
    const int f_  = blockIdx.x;
    const int xcd = f_ & 7;
    const int s_  = f_ >> 3;              // 0..255 slot within XCD
    const int b   = xcd * 4 + (s_ >> 6);  // batch (same-b => same xcd)
    const int qt  = s_ & 63;              // q-tile within batch

    const int tid = threadIdx.x, lane = tid & 63, wave = tid >> 6;
    const int lr = lane & 15, lk = lane >> 4;
    __shared__ unsigned short S[16 * SLD];      // bf16 scores, 33 KB

    const int n0 = qt * 16;
    const unsigned short* qrow = q + (size_t)(b * N_ + n0 + lr) * D_ + lk * 8;
    bf8 qa0 = *(const bf8*)(qrow);
    bf8 qa1 = *(const bf8*)(qrow + 32);

    const int m0w = wave * 256;
    #pragma unroll 4
    for (int mt = 0; mt < 16; ++mt) {
        int m = m0w + mt * 16;
        const unsigned short* krow = k + (size_t)(b * N_ + m + lr) * D_ + lk * 8;
        bf8 kb0 = *(const bf8*)(krow);
        bf8 kb1 = *(const bf8*)(krow + 32);
        f32x4 s = {0.f, 0.f, 0.f, 0.f};
        s = MFMA16(qa0, kb0, s);
        s = MFMA16(qa1, kb1, s);
        #pragma unroll
        for (int r = 0; r < 4; ++r)
            S[(lk * 4 + r) * SLD + m + lr] = f2b(s[r] * 0.125f);  // 1/sqrt(64)
    }
    __syncthreads();

    #pragma unroll
    for (int rr4 = 0; rr4 < 4; ++rr4) {
        int rr = wave * 4 + rr4;
        float vals[16];
        float mx = -1e30f;
        #pragma unroll
        for (int j = 0; j < 16; ++j) {
            vals[j] = b2f(S[rr * SLD + j * 64 + lane]);
            mx = fmaxf(mx, vals[j]);
        }
        #pragma unroll
        for (int off = 32; off; off >>= 1) mx = fmaxf(mx, __shfl_xor(mx, off));
        float sum = 0.f;
        #pragma unroll
        for (int j = 0; j < 16; ++j) { vals[j] = __expf(vals[j] - mx); sum += vals[j]; }
        #pragma unroll
        for (int off = 32; off; off >>= 1) sum += __shfl_xor(sum, off);
        float inv = 1.f / sum;
        unsigned short* pp = P + (size_t)(b * N_ + n0 + rr) * N_;
        #pragma unroll
        for (int j = 0; j < 16; ++j) pp[j * 64 + lane] = f2b(vals[j] * inv);
    }
}

// ---------------------------------------------------------------------------
// Kernel 3: O = P @ V + x (residual), fp32 out.  256x256 tile, 8 waves.
// NEW schedule: BK=32, 4 LDS buffers (tile t -> buf t&3, 3 tiles in flight),
// ONE barrier per K-step:
//   vmcnt(8); s_barrier; stage(t+3); ds_read 12xb128; lgkmcnt(0)+SB(0);
//   setprio(1); 32 MFMA; setprio(0)
// Staging buf (t+3)&3 == (t-1)&3 is safe: every wave's iter-(t-1) reads
// completed (its lgkmcnt(0)) before it passed this iter's barrier.
// vmcnt never drains to 0 until the last tile (tail 8/4/0).
// LDS 128 KB -> 1 block/CU; grid 256, XCD-bound per batch.
// ---------------------------------------------------------------------------
__global__ __launch_bounds__(512, 2) void pv(
    const unsigned short* __restrict__ P,
    const unsigned short* __restrict__ vT,
    const float* __restrict__ x,
    float* __restrict__ out)
{
    // 256 blocks: xcd = f&7; 4 batches/XCD x 8 tiles (4M x 2N of 256).
    const int f_   = blockIdx.x;
    const int xcd  = f_ & 7;
    const int s_   = f_ >> 3;             // 0..31 slot within XCD
    const int b    = xcd * 4 + (s_ >> 3); // batch (same-b => same xcd)
    const int w_   = s_ & 7;              // tile within batch
    const int m0   = (w_ & 3) * 256;
    const int c0   = (w_ >> 2) * 256;

    const int tid = threadIdx.x, lane = tid & 63, wave = tid >> 6;  // 8 waves
    const int wm = wave >> 2;             // 0..1 -> rows wm*128
    const int wn = wave & 3;              // 0..3 -> cols wn*64
    const int lr = lane & 15, lk = lane >> 4;

    __shared__ unsigned short SM[65536];  // 128 KB = 4 bufs x (A 8192 | B 8192 shorts)

    f32x4 zero4 = {0.f, 0.f, 0.f, 0.f};
    f32x4 acc[8][4];
    #pragma unroll
    for (int i = 0; i < 8; ++i)
        #pragma unroll
        for (int j = 0; j < 4; ++j) acc[i][j] = zero4;

    const unsigned short* Pb = P  + (size_t)b * N_ * N_;
    const unsigned short* Vb = vT + (size_t)b * C_ * N_;

    auto stage = [&](int t32) {           // 4 loads/thread; buf = t32&3
        unsigned short* As = SM + (t32 & 3) * 16384;
        unsigned short* Bs = As + 8192;
        const int kk = t32 * 32;
        #pragma unroll
        for (int i = 0; i < 2; ++i) {     // A frags f=wave*2+i (16 total), same B
            int f = wave * 2 + i;
            g2l16(Pb + (size_t)(m0 + f * 16 + lr) * N_ + kk + lk * 8, &As[f * 512]);
            g2l16(Vb + (size_t)(c0 + f * 16 + lr) * N_ + kk + lk * 8, &Bs[f * 512]);
        }
    };

    auto compute = [&](int t32) {
        const unsigned short* As = SM + (t32 & 3) * 16384;
        const unsigned short* Bs = As + 8192;
        bf8 a[8], bb[4];
        #pragma unroll
        for (int ti = 0; ti < 8; ++ti)
            a[ti] = *(const bf8*)&As[(wm * 8 + ti) * 512 + lane * 8];
        #pragma unroll
        for (int tj = 0; tj < 4; ++tj)
            bb[tj] = *(const bf8*)&Bs[(wn * 4 + tj) * 512 + lane * 8];
        asm volatile("s_waitcnt lgkmcnt(0)" ::: "memory");
        __builtin_amdgcn_sched_barrier(0);           // rule #18: pin MFMAs below
        __builtin_amdgcn_s_setprio(1);
        #pragma unroll
        for (int ti = 0; ti < 8; ++ti)
            #pragma unroll
            for (int tj = 0; tj < 4; ++tj)
                acc[ti][tj] = MFMA16(a[ti], bb[tj], acc[ti][tj]);
        __builtin_amdgcn_s_setprio(0);
    };

    stage(0); stage(1); stage(2);         // 12 loads/thread in flight
    for (int t = 0; t < 29; ++t) {        // steady state: tiles 0..28
        asm volatile("s_waitcnt vmcnt(8)" ::: "memory");   // my tile-t loads done
        __builtin_amdgcn_s_barrier();                      // everyone's done
        stage(t + 3);                     // into buf (t-1)&3 (reads done last iter)
        compute(t);
    }
    {   // tile 29: tiles 30,31 still in flight
        asm volatile("s_waitcnt vmcnt(8)" ::: "memory");
        __builtin_amdgcn_s_barrier();
        compute(29);
    }
    {   // tile 30
        asm volatile("s_waitcnt vmcnt(4)" ::: "memory");
        __builtin_amdgcn_s_barrier();
        compute(30);
    }
    {   // tile 31: final drain
        asm volatile("s_waitcnt vmcnt(0)" ::: "memory");
        __builtin_amdgcn_s_barrier();
        compute(31);
    }

    #pragma unroll
    for (int ti = 0; ti < 8; ++ti)
        #pragma unroll
        for (int tj = 0; tj < 4; ++tj) {
            int col = c0 + wn * 64 + tj * 16 + lr;
            #pragma unroll
            for (int r = 0; r < 4; ++r) {
                int row = m0 + wm * 128 + ti * 16 + lk * 4 + r;
                size_t idx = (size_t)(b * N_ + row) * C_ + col;
                out[idx] = acc[ti][tj][r] + x[idx];
            }
        }
}

// ---------------------------------------------------------------------------
extern "C" void kernel_launch(void* const* d_in, const int* in_sizes, int n_in,
                              void* d_out, int out_size, void* d_ws, size_t ws_size,
                              hipStream_t stream) {
    (void)in_sizes; (void)n_in; (void)out_size; (void)ws_size;
    const float* xf = (const float*)d_in[0];
    const float* wq = (const float*)d_in[1];
    const float* bq = (const float*)d_in[2];
    const float* wk = (const float*)d_in[3];
    const float* bk = (const float*)d_in[4];
    const float* wv = (const float*)d_in[5];
    const float* bv = (const float*)d_in[6];
    float* out = (float*)d_out;

    // workspace layout (bytes), total needed ~109 MB:
    //   q [0,4MB) | k [4MB,8MB) | vT [8MB,40MB)
    //   WT (655KB) + xb (32MB) in [40MB, 76MB)  -- dead after qkv
    //   P (64MB) aliased over WT+xb region starting 41,943,040
    char* ws = (char*)d_ws;
    unsigned short* qb  = (unsigned short*)(ws);
    unsigned short* kb  = (unsigned short*)(ws + 4194304);
    unsigned short* vTb = (unsigned short*)(ws + 8388608);
    unsigned short* WT  = (unsigned short*)(ws + 41943040);  // [640][512]
    unsigned short* xb  = (unsigned short*)(ws + 42598400);
    unsigned short* Pb  = (unsigned short*)(ws + 41943040);  // overlaps WT+xb

    xcvt<<<16384, 256, 0, stream>>>(xf, xb);                 // 16.7M elems
    wtrans_all<<<1280, 256, 0, stream>>>(wq, wk, wv, WT);    // all 640 rows
    qkv<<<1280, 256, 0, stream>>>(xb, WT, bq, bk, bv, qb, kb, vTb);
    scores<<<2048, 256, 0, stream>>>(qb, kb, Pb);
    pv<<<256, 512, 0, stream>>>(Pb, vTb, xf, out);
}